// Round 4
// baseline (10.814 us; speedup 1.0000x reference)
//
#include <hip/hip_runtime.h>

#define EOS_TOKEN 1

// One block, 1024 threads. B=8, S=512 => 4096 tokens, 4 CONSECUTIVE per
// thread: one int4 target load per thread, and each thread's 4 tokens lie in
// a single sequence (b = tid/128), so masking needs one s_eos read and one
// divide per thread. Gathers issue immediately after targets arrive; EOS
// search overlaps gather latency. Single data barrier.
__global__ __launch_bounds__(1024) void nll_fused_kernel(
    const float* __restrict__ input,   // [B, S, V] log-probs
    const int*   __restrict__ target,  // [B, S]
    float*       __restrict__ out,     // [1]
    int B, int S, int V)
{
    const int tid  = threadIdx.x;
    const int base = tid * 4;                 // first of this thread's 4 tokens
    const int b    = base / S;                // uniform per thread (S % 4 == 0)
    const int s0   = base - b * S;            // position of token 0 within seq

    __shared__ int   s_eos[32];               // B <= 32
    __shared__ float s_wsum[16];              // 16 waves

    if (tid < B) s_eos[tid] = S;              // sentinel
    __syncthreads();

    // Phase 1: one coalesced int4 target load per thread.
    const int4 t4 = *reinterpret_cast<const int4*>(target + base);
    const int tgt[4] = { t4.x, t4.y, t4.z, t4.w };

    // Phase 2: issue ALL gathers now (addresses independent of EOS).
    float lp[4];
    #pragma unroll
    for (int j = 0; j < 4; ++j)
        lp[j] = input[((size_t)base + j) * (size_t)V + (size_t)tgt[j]];

    // Phase 3: EOS search from registers (overlaps gather latency).
    #pragma unroll
    for (int j = 0; j < 4; ++j)
        if (tgt[j] == EOS_TOKEN) atomicMin(&s_eos[b], s0 + j);
    __syncthreads();

    // Phase 4: masked accumulate; inv factored out (one divide per thread).
    const int   eos = s_eos[b];
    const float inv = 1.0f / (float)eos;
    float sum = 0.0f;
    #pragma unroll
    for (int j = 0; j < 4; ++j)
        if (s0 + j <= eos) sum += lp[j];
    float acc = -sum * inv;

    // Phase 5: block reduction (64-lane shuffle, then cross-wave LDS).
    #pragma unroll
    for (int off = 32; off > 0; off >>= 1)
        acc += __shfl_down(acc, off, 64);

    const int lane = tid & 63;
    const int wid  = tid >> 6;
    if (lane == 0) s_wsum[wid] = acc;
    __syncthreads();

    if (tid == 0) {
        float total = 0.0f;
        #pragma unroll
        for (int w = 0; w < 16; ++w) total += s_wsum[w];
        out[0] = total;                       // overwrite: deterministic
    }
}

extern "C" void kernel_launch(void* const* d_in, const int* in_sizes, int n_in,
                              void* d_out, int out_size, void* d_ws, size_t ws_size,
                              hipStream_t stream)
{
    const float* input  = (const float*)d_in[0];
    const int*   target = (const int*)d_in[1];
    float*       out    = (float*)d_out;

    const int S  = 512;
    const int BS = in_sizes[1];          // B*S
    const int B  = BS / S;
    const int V  = (int)((long long)in_sizes[0] / (long long)BS);

    nll_fused_kernel<<<1, 1024, 0, stream>>>(input, target, out, B, S, V);
}

// Round 5
// 9.708 us; speedup vs baseline: 1.1139x; 1.1139x over previous
//
#include <hip/hip_runtime.h>

#define EOS_TOKEN 1

// One block, 1024 threads. B=8, S=512 => 4096 tokens, 4 consecutive per
// thread. Critical chain: int4 target load -> 4 gathers -> masked sum.
// Everything else (s_eos init, barrier, EOS atomicMin) overlaps load latency.
__global__ __launch_bounds__(1024) void nll_fused_kernel(
    const float* __restrict__ input,   // [B, S, V] log-probs
    const int*   __restrict__ target,  // [B, S]
    float*       __restrict__ out,     // [1]
    int B, int S, int V)
{
    const int tid  = threadIdx.x;
    const int base = tid * 4;                 // this thread's 4 tokens
    const int b    = base / S;                // uniform per thread (S%4==0)
    const int s0   = base - b * S;

    __shared__ int   s_eos[32];               // B <= 32
    __shared__ float s_wsum[16];              // 16 waves

    // Issue the target load FIRST; everything until the gather addr calc
    // overlaps its latency.
    const int4 t4 = *reinterpret_cast<const int4*>(target + base);

    if (tid < B) s_eos[tid] = S;              // sentinel
    __syncthreads();                          // hides under the load

    const int tgt[4] = { t4.x, t4.y, t4.z, t4.w };

    // Gathers: unconditional, issue ASAP (addresses independent of EOS).
    float lp[4];
    #pragma unroll
    for (int j = 0; j < 4; ++j)
        lp[j] = input[((size_t)base + j) * (size_t)V + (size_t)tgt[j]];

    // EOS search overlaps gather latency.
    #pragma unroll
    for (int j = 0; j < 4; ++j)
        if (tgt[j] == EOS_TOKEN) atomicMin(&s_eos[b], s0 + j);
    __syncthreads();

    const int   eos = s_eos[b];
    const float inv = 1.0f / (float)eos;
    float sum = 0.0f;
    #pragma unroll
    for (int j = 0; j < 4; ++j)
        if (s0 + j <= eos) sum += lp[j];
    float acc = -sum * inv;

    // Wave reduce (64 lanes), then wave 0 reduces the 16 partials.
    #pragma unroll
    for (int off = 32; off > 0; off >>= 1)
        acc += __shfl_down(acc, off, 64);

    const int lane = tid & 63;
    const int wid  = tid >> 6;
    if (lane == 0) s_wsum[wid] = acc;
    __syncthreads();

    if (wid == 0) {
        float v = (lane < 16) ? s_wsum[lane] : 0.0f;
        #pragma unroll
        for (int off = 8; off > 0; off >>= 1)
            v += __shfl_down(v, off, 64);
        if (lane == 0) out[0] = v;            // overwrite: deterministic
    }
}

extern "C" void kernel_launch(void* const* d_in, const int* in_sizes, int n_in,
                              void* d_out, int out_size, void* d_ws, size_t ws_size,
                              hipStream_t stream)
{
    const float* input  = (const float*)d_in[0];
    const int*   target = (const int*)d_in[1];
    float*       out    = (float*)d_out;

    const int S  = 512;
    const int BS = in_sizes[1];          // B*S
    const int B  = BS / S;
    const int V  = (int)((long long)in_sizes[0] / (long long)BS);

    nll_fused_kernel<<<1, 1024, 0, stream>>>(input, target, out, B, S, V);
}